// Round 2
// baseline (1113.871 us; speedup 1.0000x reference)
//
#include <hip/hip_runtime.h>
#include <cmath>

// Problem constants
#define BATCH 4
#define SEQ   2048
#define EMB   2048
#define NH    16
#define HD    128
#define MDIM  (BATCH*SEQ)   // 8192
#define KDIM  EMB           // 2048
#define NDIM  EMB           // 2048

typedef __bf16 bf16x8 __attribute__((ext_vector_type(8)));
typedef float  f32x4  __attribute__((ext_vector_type(4)));

// async global->LDS, 16B per lane; LDS dest is wave-uniform base + lane*16
#define GLDS16(gp, lp) \
  __builtin_amdgcn_global_load_lds((const __attribute__((address_space(1))) void*)(gp), \
                                   (__attribute__((address_space(3))) void*)(lp), 16, 0, 0)

__device__ __forceinline__ ushort bf16rne(float f) {
  unsigned u = __builtin_bit_cast(unsigned, f);
  u += 0x7fffu + ((u >> 16) & 1u);
  return (ushort)(u >> 16);
}

// ---------------- fp32 -> bf16 convert (vector x4) ----------------
__global__ __launch_bounds__(256) void cvt_bf16(const float* __restrict__ in,
                                                ushort* __restrict__ out) {
  int i = (blockIdx.x * 256 + threadIdx.x) * 4;
  float4 v = *(const float4*)(in + i);
  ushort4 o;
  o.x = bf16rne(v.x); o.y = bf16rne(v.y); o.z = bf16rne(v.z); o.w = bf16rne(v.w);
  *(ushort4*)(out + i) = o;
}

// ---------------- NT GEMM (m97 structure): C[M,N] = A[M,K]*B[N,K]^T + bias --
// MODE 0: fp32 plain row-major [M,N]
// MODE 1: bf16 to [B,H,S,D]   (m = b*S+s, n = h*D+d)
// MODE 2: bf16 to [B,H,D,S]   (transposed store via LDS)
template<int MODE>
__global__ __launch_bounds__(256, 2)
void gemm_nt(const ushort* __restrict__ A, const ushort* __restrict__ Bm,
             const float* __restrict__ bias, void* __restrict__ out) {
  // UNPADDED: required by global_load_lds (lane-contiguous dest)
  __shared__ __attribute__((aligned(16))) ushort As[128 * 64];
  __shared__ __attribute__((aligned(16))) ushort Bs[128 * 64];

  const int tid  = threadIdx.x;
  const int wave = tid >> 6, lane = tid & 63;
  const int l15  = lane & 15, quad = lane >> 4;
  const int m0 = blockIdx.x * 128, n0 = blockIdx.y * 128;
  const int wr = (wave >> 1) * 64, wc = (wave & 1) * 64;

  // staging: chunk ci = wave*4+c covers rows ci*8..ci*8+7 (128B rows)
  const ushort* ag[4]; const ushort* bg[4];
  ushort* la[4]; ushort* lb[4];
#pragma unroll
  for (int c = 0; c < 4; ++c) {
    int ci  = wave * 4 + c;
    int row = ci * 8 + (lane >> 3);
    int col = (lane & 7) * 8;
    ag[c] = A  + (size_t)(m0 + row) * KDIM + col;
    bg[c] = Bm + (size_t)(n0 + row) * KDIM + col;
    la[c] = &As[ci * 512];
    lb[c] = &Bs[ci * 512];
  }

  const f32x4 zero4 = {0.f, 0.f, 0.f, 0.f};
  f32x4 acc[4][4];
#pragma unroll
  for (int i = 0; i < 4; ++i)
#pragma unroll
    for (int j = 0; j < 4; ++j) acc[i][j] = zero4;

  for (int kk = 0; kk < KDIM; kk += 64) {
#pragma unroll
    for (int c = 0; c < 4; ++c) {
      GLDS16(ag[c], la[c]);
      GLDS16(bg[c], lb[c]);
      ag[c] += 64; bg[c] += 64;
    }
    __syncthreads();
#pragma unroll
    for (int ks = 0; ks < 2; ++ks) {
      bf16x8 af[4], bfr[4];
#pragma unroll
      for (int i = 0; i < 4; ++i)
        af[i] = __builtin_bit_cast(bf16x8, *(const int4*)(&As[(wr + i*16 + l15) * 64 + ks*32 + quad*8]));
#pragma unroll
      for (int j = 0; j < 4; ++j)
        bfr[j] = __builtin_bit_cast(bf16x8, *(const int4*)(&Bs[(wc + j*16 + l15) * 64 + ks*32 + quad*8]));
#pragma unroll
      for (int i = 0; i < 4; ++i)
#pragma unroll
        for (int j = 0; j < 4; ++j)
          acc[i][j] = __builtin_amdgcn_mfma_f32_16x16x32_bf16(af[i], bfr[j], acc[i][j], 0, 0, 0);
    }
    __syncthreads();
  }

  // Epilogue. C/D layout: col = lane&15, row = quad*4 + r  (m89/m91 verified)
  if constexpr (MODE == 0) {
    float* O = (float*)out;
#pragma unroll
    for (int i = 0; i < 4; ++i)
#pragma unroll
      for (int j = 0; j < 4; ++j) {
        int n = n0 + wc + j*16 + l15;
        float bb = bias[n];
#pragma unroll
        for (int r = 0; r < 4; ++r) {
          int m = m0 + wr + i*16 + quad*4 + r;
          O[(size_t)m * NDIM + n] = acc[i][j][r] + bb;
        }
      }
  } else if constexpr (MODE == 1) {
    ushort* O = (ushort*)out;
#pragma unroll
    for (int i = 0; i < 4; ++i)
#pragma unroll
      for (int j = 0; j < 4; ++j) {
        int n = n0 + wc + j*16 + l15;
        float bb = bias[n];
        int h = n >> 7, d = n & 127;
#pragma unroll
        for (int r = 0; r < 4; ++r) {
          int m = m0 + wr + i*16 + quad*4 + r;
          int b = m >> 11, srow = m & 2047;
          O[(((size_t)(b*NH + h) * SEQ + srow) << 7) + d] = bf16rne(acc[i][j][r] + bb);
        }
      }
  } else {  // MODE 2: [B,H,D,S] via per-wave LDS 16x16 transpose
    __shared__ float Tt[4][16][17];
    ushort* O = (ushort*)out;
    const int h = n0 >> 7;   // N-tile(128) == one head
#pragma unroll
    for (int i = 0; i < 4; ++i)
#pragma unroll
      for (int j = 0; j < 4; ++j) {
        int n = n0 + wc + j*16 + l15;
        float bb = bias[n];
#pragma unroll
        for (int r = 0; r < 4; ++r)
          Tt[wave][l15][quad*4 + r] = acc[i][j][r] + bb;   // Tt[d_local][s_local]
#pragma unroll
        for (int r = 0; r < 4; ++r) {
          int dl = quad*4 + r, sl = l15;
          float v = Tt[wave][dl][sl];
          int m = m0 + wr + i*16 + sl;
          int b = m >> 11, srow = m & 2047;
          int d = wc + j*16 + dl;
          O[((size_t)(b*NH + h) * HD + d) * SEQ + srow] = bf16rne(v);
        }
      }
  }
}

// ---------------- fused attention (no-max online softmax), q-tile=128 -------
// Qh,Kh: bf16 [B,H,S,D]; Vt: bf16 [B,H,D,S]; noise fp32 [B,S,E];
// ctxn: bf16 [B*S, E] = softmax(QK^T * scale) V + noise*ns
__global__ __launch_bounds__(256, 2)
void attn_kernel(const ushort* __restrict__ Qh, const ushort* __restrict__ Kh,
                 const ushort* __restrict__ Vt, const float* __restrict__ noise,
                 ushort* __restrict__ ctxn, float scale, float ns) {
  __shared__ __attribute__((aligned(16))) ushort Ks[64 * 128];  // [k][d] unpadded
  __shared__ __attribute__((aligned(16))) ushort Vs[128 * 64];  // [d][k] unpadded
  __shared__ ushort Ps[128][72];                                // [q][k] padded (manual writes)

  const int tid  = threadIdx.x;
  const int wave = tid >> 6, lane = tid & 63;
  const int l15  = lane & 15, quad = lane >> 4;
  const int q0 = blockIdx.x * 128;
  const int bh = blockIdx.y;                  // b*NH + h
  const int b  = bh >> 4, h = bh & 15;

  // Q fragments: 2 strips of 16 q-rows per wave, kept in registers
  bf16x8 qf[2][4];
#pragma unroll
  for (int s = 0; s < 2; ++s) {
    const int qrow = q0 + s*64 + wave*16 + l15;
    const ushort* qp = Qh + ((size_t)bh * SEQ + qrow) * HD;
#pragma unroll
    for (int ks = 0; ks < 4; ++ks)
      qf[s][ks] = __builtin_bit_cast(bf16x8, *(const int4*)(qp + ks*32 + quad*8));
  }

  // staging pointers
  const ushort* kg[4]; const ushort* vg[4];
  ushort* lk[4]; ushort* lv[4];
#pragma unroll
  for (int c = 0; c < 4; ++c) {
    int ci = wave * 4 + c;
    // K: rows of 256B -> chunk = 4 rows; lane row = lane>>4, col16 = lane&15
    int kr = ci * 4 + (lane >> 4);
    kg[c] = Kh + ((size_t)bh * SEQ + kr) * HD + (lane & 15) * 8;
    lk[c] = &Ks[ci * 512];
    // V^T: rows of 128B -> chunk = 8 rows; lane row = lane>>3, col16 = lane&7
    int vr = ci * 8 + (lane >> 3);
    vg[c] = Vt + ((size_t)bh * HD + vr) * SEQ + (lane & 7) * 8;
    lv[c] = &Vs[ci * 512];
  }

  const f32x4 zero4 = {0.f, 0.f, 0.f, 0.f};
  f32x4 o[2][8];
#pragma unroll
  for (int s = 0; s < 2; ++s)
#pragma unroll
    for (int nb = 0; nb < 8; ++nb) o[s][nb] = zero4;
  float rs[2][4] = {{0.f,0.f,0.f,0.f},{0.f,0.f,0.f,0.f}};

  for (int k0 = 0; k0 < SEQ; k0 += 64) {
#pragma unroll
    for (int c = 0; c < 4; ++c) {
      GLDS16(kg[c], lk[c]);
      GLDS16(vg[c], lv[c]);
      kg[c] += (size_t)64 * HD;  // next 64 key rows
      vg[c] += 64;               // next 64 key cols
    }
    __syncthreads();

    // S = Q K^T -> exp -> Ps (LDS round trip, C-layout -> A-layout); wave-private rows
#pragma unroll
    for (int s = 0; s < 2; ++s)
#pragma unroll
      for (int ct = 0; ct < 4; ++ct) {
        f32x4 sc = zero4;
#pragma unroll
        for (int ks = 0; ks < 4; ++ks) {
          bf16x8 kf = __builtin_bit_cast(bf16x8, *(const int4*)(&Ks[(ct*16 + l15) * 128 + ks*32 + quad*8]));
          sc = __builtin_amdgcn_mfma_f32_16x16x32_bf16(qf[s][ks], kf, sc, 0, 0, 0);
        }
#pragma unroll
        for (int r = 0; r < 4; ++r) {
          float p = __expf(sc[r] * scale);
          rs[s][r] += p;
          Ps[s*64 + wave*16 + quad*4 + r][ct*16 + l15] = bf16rne(p);
        }
      }

    // O += P V   (V frags shared across both q-strips)
#pragma unroll
    for (int ks2 = 0; ks2 < 2; ++ks2) {
      bf16x8 vb[8];
#pragma unroll
      for (int nb = 0; nb < 8; ++nb)
        vb[nb] = __builtin_bit_cast(bf16x8, *(const int4*)(&Vs[(nb*16 + l15) * 64 + ks2*32 + quad*8]));
#pragma unroll
      for (int s = 0; s < 2; ++s) {
        bf16x8 pa = __builtin_bit_cast(bf16x8, *(const int4*)(&Ps[s*64 + wave*16 + l15][ks2*32 + quad*8]));
#pragma unroll
        for (int nb = 0; nb < 8; ++nb)
          o[s][nb] = __builtin_amdgcn_mfma_f32_16x16x32_bf16(pa, vb[nb], o[s][nb], 0, 0, 0);
      }
    }
    __syncthreads();
  }

  // row sums: reduce across the 16 lanes of each quad; then epilogue
#pragma unroll
  for (int s = 0; s < 2; ++s) {
#pragma unroll
    for (int r = 0; r < 4; ++r) {
      float v = rs[s][r];
      v += __shfl_xor(v, 1);
      v += __shfl_xor(v, 2);
      v += __shfl_xor(v, 4);
      v += __shfl_xor(v, 8);
      rs[s][r] = v;
    }
#pragma unroll
    for (int r = 0; r < 4; ++r) {
      float inv = 1.0f / rs[s][r];
      int sg = q0 + s*64 + wave*16 + quad*4 + r;
      size_t rowbase = ((size_t)(b * SEQ + sg)) * EMB + h * HD;
#pragma unroll
      for (int nb = 0; nb < 8; ++nb) {
        int e = nb*16 + l15;
        float val = o[s][nb][r] * inv + noise[rowbase + e] * ns;
        ctxn[rowbase + e] = bf16rne(val);
      }
    }
  }
}

extern "C" void kernel_launch(void* const* d_in, const int* in_sizes, int n_in,
                              void* d_out, int out_size, void* d_ws, size_t ws_size,
                              hipStream_t stream) {
  const float* query = (const float*)d_in[0];
  const float* key_t = (const float*)d_in[1];
  const float* value = (const float*)d_in[2];
  const float* Wq = (const float*)d_in[3];
  const float* bq = (const float*)d_in[4];
  const float* Wk = (const float*)d_in[5];
  const float* bk = (const float*)d_in[6];
  const float* Wv = (const float*)d_in[7];
  const float* bv = (const float*)d_in[8];
  const float* Wo = (const float*)d_in[9];
  const float* bo = (const float*)d_in[10];
  const float* noise = (const float*)d_in[11];

  const size_t SZ_ACT = (size_t)MDIM * KDIM * 2;  // 33,554,432 B
  const size_t SZ_W   = (size_t)NDIM * KDIM * 2;  //  8,388,608 B
  const size_t need_full = 7 * SZ_ACT + 4 * SZ_W; // 256 MB

  char* p = (char*)d_ws;
  ushort *qb, *kb;
  if (ws_size >= need_full) {
    qb = (ushort*)p; p += SZ_ACT;
    kb = (ushort*)p; p += SZ_ACT;
  } else {
    // overlay q/k bf16 inputs on d_out (exactly 64 MB); consumed before final GEMM
    qb = (ushort*)d_out;
    kb = (ushort*)((char*)d_out + SZ_ACT);
  }
  ushort* vb   = (ushort*)p; p += SZ_ACT;
  ushort* wqb  = (ushort*)p; p += SZ_W;
  ushort* wkb  = (ushort*)p; p += SZ_W;
  ushort* wvb  = (ushort*)p; p += SZ_W;
  ushort* wob  = (ushort*)p; p += SZ_W;
  ushort* Qh   = (ushort*)p; p += SZ_ACT;
  ushort* Kh   = (ushort*)p; p += SZ_ACT;
  ushort* Vt   = (ushort*)p; p += SZ_ACT;
  ushort* ctxn = (ushort*)p; p += SZ_ACT;

  const int nAct = MDIM * KDIM;          // 16,777,216
  const int nW   = NDIM * KDIM;          //  4,194,304
  const float NS = (float)sqrt(2.0 * log(1.25 / 1e-5));
  const float SCALE = (float)(1.0 / sqrt((double)HD));

  cvt_bf16<<<dim3(nAct / 1024), dim3(256), 0, stream>>>(query, qb);
  cvt_bf16<<<dim3(nAct / 1024), dim3(256), 0, stream>>>(key_t, kb);
  cvt_bf16<<<dim3(nAct / 1024), dim3(256), 0, stream>>>(value, vb);
  cvt_bf16<<<dim3(nW / 1024),   dim3(256), 0, stream>>>(Wq, wqb);
  cvt_bf16<<<dim3(nW / 1024),   dim3(256), 0, stream>>>(Wk, wkb);
  cvt_bf16<<<dim3(nW / 1024),   dim3(256), 0, stream>>>(Wv, wvb);
  cvt_bf16<<<dim3(nW / 1024),   dim3(256), 0, stream>>>(Wo, wob);

  dim3 ggrid(MDIM / 128, NDIM / 128);   // 64 x 16
  gemm_nt<1><<<ggrid, dim3(256), 0, stream>>>(qb, wqb, bq, (void*)Qh);
  gemm_nt<1><<<ggrid, dim3(256), 0, stream>>>(kb, wkb, bk, (void*)Kh);
  gemm_nt<2><<<ggrid, dim3(256), 0, stream>>>(vb, wvb, bv, (void*)Vt);

  attn_kernel<<<dim3(SEQ / 128, BATCH * NH), dim3(256), 0, stream>>>(
      Qh, Kh, Vt, noise, ctxn, SCALE, NS);

  gemm_nt<0><<<ggrid, dim3(256), 0, stream>>>(ctxn, wob, bo, d_out);
}

// Round 3
// 941.238 us; speedup vs baseline: 1.1834x; 1.1834x over previous
//
#include <hip/hip_runtime.h>
#include <cmath>

// Problem constants
#define BATCH 4
#define SEQ   2048
#define EMB   2048
#define NH    16
#define HD    128
#define MDIM  (BATCH*SEQ)   // 8192
#define KDIM  EMB           // 2048
#define NDIM  EMB           // 2048

typedef __bf16 bf16x8 __attribute__((ext_vector_type(8)));
typedef float  f32x4  __attribute__((ext_vector_type(4)));

// async global->LDS, 16B per lane; LDS dest is wave-uniform base + lane*16
#define GLDS16(gp, lp) \
  __builtin_amdgcn_global_load_lds((const __attribute__((address_space(1))) void*)(gp), \
                                   (__attribute__((address_space(3))) void*)(lp), 16, 0, 0)

__device__ __forceinline__ ushort bf16rne(float f) {
  unsigned u = __builtin_bit_cast(unsigned, f);
  u += 0x7fffu + ((u >> 16) & 1u);
  return (ushort)(u >> 16);
}

// ---------------- fp32 -> bf16 convert (vector x4) ----------------
__global__ __launch_bounds__(256) void cvt_bf16(const float* __restrict__ in,
                                                ushort* __restrict__ out) {
  int i = (blockIdx.x * 256 + threadIdx.x) * 4;
  float4 v = *(const float4*)(in + i);
  ushort4 o;
  o.x = bf16rne(v.x); o.y = bf16rne(v.y); o.z = bf16rne(v.z); o.w = bf16rne(v.w);
  *(ushort4*)(out + i) = o;
}

// ---------------- NT GEMM (m97 + XOR swizzle): C = A[M,K]*B[N,K]^T + bias ---
// LDS layout: row r, 16B-chunk position p holds global chunk (p ^ (r&7)).
// Staging global_load_lds writes lane*16 contiguous; we permute the global
// source per lane to realize the swizzle. Frag reads XOR the chunk index.
// MODE 0: fp32 plain row-major [M,N]
// MODE 1: bf16 to [B,H,S,D]   (m = b*S+s, n = h*D+d)
// MODE 2: bf16 to [B,H,D,S]   (transposed store via LDS)
template<int MODE>
__global__ __launch_bounds__(256, 3)
void gemm_nt(const ushort* __restrict__ A, const ushort* __restrict__ Bm,
             const float* __restrict__ bias, void* __restrict__ out) {
  __shared__ __attribute__((aligned(16))) ushort As[128 * 64];
  __shared__ __attribute__((aligned(16))) ushort Bs[128 * 64];

  const int tid  = threadIdx.x;
  const int wave = tid >> 6, lane = tid & 63;
  const int l15  = lane & 15, quad = lane >> 4;
  const int m0 = blockIdx.x * 128, n0 = blockIdx.y * 128;
  const int wr = (wave >> 1) * 64, wc = (wave & 1) * 64;
  const int sw = l15 & 7;          // frag-read swizzle key (= row&7)

  // staging: chunk ci = wave*4+c covers rows ci*8..ci*8+7 (128B rows)
  // lane -> row = ci*8 + lane>>3, LDS chunk pos = lane&7,
  // global col chunk = (lane&7) ^ (row&7) = (lane&7) ^ (lane>>3)
  const ushort* ag[4]; const ushort* bg[4];
  ushort* la[4]; ushort* lb[4];
#pragma unroll
  for (int c = 0; c < 4; ++c) {
    int ci  = wave * 4 + c;
    int row = ci * 8 + (lane >> 3);
    int col = ((lane & 7) ^ (lane >> 3)) * 8;
    ag[c] = A  + (size_t)(m0 + row) * KDIM + col;
    bg[c] = Bm + (size_t)(n0 + row) * KDIM + col;
    la[c] = &As[ci * 512];
    lb[c] = &Bs[ci * 512];
  }

  const f32x4 zero4 = {0.f, 0.f, 0.f, 0.f};
  f32x4 acc[4][4];
#pragma unroll
  for (int i = 0; i < 4; ++i)
#pragma unroll
    for (int j = 0; j < 4; ++j) acc[i][j] = zero4;

  for (int kk = 0; kk < KDIM; kk += 64) {
#pragma unroll
    for (int c = 0; c < 4; ++c) {
      GLDS16(ag[c], la[c]);
      GLDS16(bg[c], lb[c]);
      ag[c] += 64; bg[c] += 64;
    }
    __syncthreads();
#pragma unroll
    for (int ks = 0; ks < 2; ++ks) {
      bf16x8 af[4], bfr[4];
#pragma unroll
      for (int i = 0; i < 4; ++i) {
        int p0 = ((ks*4 + quad) ^ sw) * 8;
        af[i] = __builtin_bit_cast(bf16x8, *(const int4*)(&As[(wr + i*16 + l15) * 64 + p0]));
      }
#pragma unroll
      for (int j = 0; j < 4; ++j) {
        int p0 = ((ks*4 + quad) ^ sw) * 8;
        bfr[j] = __builtin_bit_cast(bf16x8, *(const int4*)(&Bs[(wc + j*16 + l15) * 64 + p0]));
      }
#pragma unroll
      for (int i = 0; i < 4; ++i)
#pragma unroll
        for (int j = 0; j < 4; ++j)
          acc[i][j] = __builtin_amdgcn_mfma_f32_16x16x32_bf16(af[i], bfr[j], acc[i][j], 0, 0, 0);
    }
    __syncthreads();
  }

  // Epilogue. C/D layout: col = lane&15, row = quad*4 + r  (m89/m91 verified)
  if constexpr (MODE == 0) {
    float* O = (float*)out;
#pragma unroll
    for (int i = 0; i < 4; ++i)
#pragma unroll
      for (int j = 0; j < 4; ++j) {
        int n = n0 + wc + j*16 + l15;
        float bb = bias[n];
#pragma unroll
        for (int r = 0; r < 4; ++r) {
          int m = m0 + wr + i*16 + quad*4 + r;
          O[(size_t)m * NDIM + n] = acc[i][j][r] + bb;
        }
      }
  } else if constexpr (MODE == 1) {
    ushort* O = (ushort*)out;
#pragma unroll
    for (int i = 0; i < 4; ++i)
#pragma unroll
      for (int j = 0; j < 4; ++j) {
        int n = n0 + wc + j*16 + l15;
        float bb = bias[n];
        int h = n >> 7, d = n & 127;
#pragma unroll
        for (int r = 0; r < 4; ++r) {
          int m = m0 + wr + i*16 + quad*4 + r;
          int b = m >> 11, srow = m & 2047;
          O[(((size_t)(b*NH + h) * SEQ + srow) << 7) + d] = bf16rne(acc[i][j][r] + bb);
        }
      }
  } else {  // MODE 2: [B,H,D,S] via per-wave LDS 16x16 transpose
    __shared__ float Tt[4][16][17];
    ushort* O = (ushort*)out;
    const int h = n0 >> 7;   // N-tile(128) == one head
#pragma unroll
    for (int i = 0; i < 4; ++i)
#pragma unroll
      for (int j = 0; j < 4; ++j) {
        int n = n0 + wc + j*16 + l15;
        float bb = bias[n];
#pragma unroll
        for (int r = 0; r < 4; ++r)
          Tt[wave][l15][quad*4 + r] = acc[i][j][r] + bb;   // Tt[d_local][s_local]
#pragma unroll
        for (int r = 0; r < 4; ++r) {
          int dl = quad*4 + r, sl = l15;
          float v = Tt[wave][dl][sl];
          int m = m0 + wr + i*16 + sl;
          int b = m >> 11, srow = m & 2047;
          int d = wc + j*16 + dl;
          O[((size_t)(b*NH + h) * HD + d) * SEQ + srow] = bf16rne(v);
        }
      }
  }
}

// ---------------- fused attention (no-max online softmax), q-tile=128 -------
// Qh,Kh: bf16 [B,H,S,D]; Vt: bf16 [B,H,D,S]; noise fp32 [B,S,E];
// ctxn: bf16 [B*S, E] = softmax(QK^T * scale) V + noise*ns
__global__ __launch_bounds__(256, 3)
void attn_kernel(const ushort* __restrict__ Qh, const ushort* __restrict__ Kh,
                 const ushort* __restrict__ Vt, const float* __restrict__ noise,
                 ushort* __restrict__ ctxn, float scale, float ns) {
  __shared__ __attribute__((aligned(16))) ushort Ks[64 * 128];  // [k][d] swizzled
  __shared__ __attribute__((aligned(16))) ushort Vs[128 * 64];  // [d][k] swizzled
  __shared__ ushort Ps[128][68];   // [q][k] padded; 68 -> quads on distinct bank groups

  const int tid  = threadIdx.x;
  const int wave = tid >> 6, lane = tid & 63;
  const int l15  = lane & 15, quad = lane >> 4;
  const int sw = l15 & 7;
  const int q0 = blockIdx.x * 128;
  const int bh = blockIdx.y;                  // b*NH + h
  const int b  = bh >> 4, h = bh & 15;

  // Q fragments: 2 strips of 16 q-rows per wave, kept in registers
  bf16x8 qf[2][4];
#pragma unroll
  for (int s = 0; s < 2; ++s) {
    const int qrow = q0 + s*64 + wave*16 + l15;
    const ushort* qp = Qh + ((size_t)bh * SEQ + qrow) * HD;
#pragma unroll
    for (int ks = 0; ks < 4; ++ks)
      qf[s][ks] = __builtin_bit_cast(bf16x8, *(const int4*)(qp + ks*32 + quad*8));
  }

  // staging pointers (swizzled global source, contiguous LDS dest)
  const ushort* kg[4]; const ushort* vg[4];
  ushort* lk[4]; ushort* lv[4];
#pragma unroll
  for (int c = 0; c < 4; ++c) {
    int ci = wave * 4 + c;
    // K: rows of 256B (16 chunks); chunk ci covers 4 rows
    int kr = ci * 4 + (lane >> 4);
    int kc = ((lane & 15) ^ (kr & 7)) * 8;
    kg[c] = Kh + ((size_t)bh * SEQ + kr) * HD + kc;
    lk[c] = &Ks[ci * 512];
    // V^T: rows of 128B (8 chunks); chunk ci covers 8 rows
    int vr = ci * 8 + (lane >> 3);
    int vc = ((lane & 7) ^ (vr & 7)) * 8;
    vg[c] = Vt + ((size_t)bh * HD + vr) * SEQ + vc;
    lv[c] = &Vs[ci * 512];
  }

  const f32x4 zero4 = {0.f, 0.f, 0.f, 0.f};
  f32x4 o[2][8];
#pragma unroll
  for (int s = 0; s < 2; ++s)
#pragma unroll
    for (int nb = 0; nb < 8; ++nb) o[s][nb] = zero4;
  float rs[2][4] = {{0.f,0.f,0.f,0.f},{0.f,0.f,0.f,0.f}};

  for (int k0 = 0; k0 < SEQ; k0 += 64) {
#pragma unroll
    for (int c = 0; c < 4; ++c) {
      GLDS16(kg[c], lk[c]);
      GLDS16(vg[c], lv[c]);
      kg[c] += (size_t)64 * HD;  // next 64 key rows
      vg[c] += 64;               // next 64 key cols
    }
    __syncthreads();

    // S = Q K^T -> exp -> Ps (C-layout -> A-layout via LDS); wave-private rows
#pragma unroll
    for (int s = 0; s < 2; ++s)
#pragma unroll
      for (int ct = 0; ct < 4; ++ct) {
        f32x4 sc = zero4;
#pragma unroll
        for (int ks = 0; ks < 4; ++ks) {
          int p0 = ((ks*4 + quad) ^ sw) * 8;
          bf16x8 kf = __builtin_bit_cast(bf16x8, *(const int4*)(&Ks[(ct*16 + l15) * 128 + p0]));
          sc = __builtin_amdgcn_mfma_f32_16x16x32_bf16(qf[s][ks], kf, sc, 0, 0, 0);
        }
#pragma unroll
        for (int r = 0; r < 4; ++r) {
          float p = __expf(sc[r] * scale);
          rs[s][r] += p;
          Ps[s*64 + wave*16 + quad*4 + r][ct*16 + l15] = bf16rne(p);
        }
      }

    // O += P V   (V frags shared across both q-strips)
#pragma unroll
    for (int ks2 = 0; ks2 < 2; ++ks2) {
      bf16x8 vb[8];
#pragma unroll
      for (int nb = 0; nb < 8; ++nb) {
        int p0 = ((ks2*4 + quad) ^ sw) * 8;
        vb[nb] = __builtin_bit_cast(bf16x8, *(const int4*)(&Vs[(nb*16 + l15) * 64 + p0]));
      }
#pragma unroll
      for (int s = 0; s < 2; ++s) {
        bf16x8 pa = __builtin_bit_cast(bf16x8, *(const int4*)(&Ps[s*64 + wave*16 + l15][ks2*32 + quad*8]));
#pragma unroll
        for (int nb = 0; nb < 8; ++nb)
          o[s][nb] = __builtin_amdgcn_mfma_f32_16x16x32_bf16(pa, vb[nb], o[s][nb], 0, 0, 0);
      }
    }
    __syncthreads();
  }

  // row sums: reduce across the 16 lanes of each quad; then epilogue
#pragma unroll
  for (int s = 0; s < 2; ++s) {
#pragma unroll
    for (int r = 0; r < 4; ++r) {
      float v = rs[s][r];
      v += __shfl_xor(v, 1);
      v += __shfl_xor(v, 2);
      v += __shfl_xor(v, 4);
      v += __shfl_xor(v, 8);
      rs[s][r] = v;
    }
#pragma unroll
    for (int r = 0; r < 4; ++r) {
      float inv = 1.0f / rs[s][r];
      int sg = q0 + s*64 + wave*16 + quad*4 + r;
      size_t rowbase = ((size_t)(b * SEQ + sg)) * EMB + h * HD;
#pragma unroll
      for (int nb = 0; nb < 8; ++nb) {
        int e = nb*16 + l15;
        float val = o[s][nb][r] * inv + noise[rowbase + e] * ns;
        ctxn[rowbase + e] = bf16rne(val);
      }
    }
  }
}

extern "C" void kernel_launch(void* const* d_in, const int* in_sizes, int n_in,
                              void* d_out, int out_size, void* d_ws, size_t ws_size,
                              hipStream_t stream) {
  const float* query = (const float*)d_in[0];
  const float* key_t = (const float*)d_in[1];
  const float* value = (const float*)d_in[2];
  const float* Wq = (const float*)d_in[3];
  const float* bq = (const float*)d_in[4];
  const float* Wk = (const float*)d_in[5];
  const float* bk = (const float*)d_in[6];
  const float* Wv = (const float*)d_in[7];
  const float* bv = (const float*)d_in[8];
  const float* Wo = (const float*)d_in[9];
  const float* bo = (const float*)d_in[10];
  const float* noise = (const float*)d_in[11];

  const size_t SZ_ACT = (size_t)MDIM * KDIM * 2;  // 33,554,432 B
  const size_t SZ_W   = (size_t)NDIM * KDIM * 2;  //  8,388,608 B
  const size_t need_full = 7 * SZ_ACT + 4 * SZ_W; // 256 MB

  char* p = (char*)d_ws;
  ushort *qb, *kb;
  if (ws_size >= need_full) {
    qb = (ushort*)p; p += SZ_ACT;
    kb = (ushort*)p; p += SZ_ACT;
  } else {
    // overlay q/k bf16 inputs on d_out (exactly 64 MB); consumed before final GEMM
    qb = (ushort*)d_out;
    kb = (ushort*)((char*)d_out + SZ_ACT);
  }
  ushort* vb   = (ushort*)p; p += SZ_ACT;
  ushort* wqb  = (ushort*)p; p += SZ_W;
  ushort* wkb  = (ushort*)p; p += SZ_W;
  ushort* wvb  = (ushort*)p; p += SZ_W;
  ushort* wob  = (ushort*)p; p += SZ_W;
  ushort* Qh   = (ushort*)p; p += SZ_ACT;
  ushort* Kh   = (ushort*)p; p += SZ_ACT;
  ushort* Vt   = (ushort*)p; p += SZ_ACT;
  ushort* ctxn = (ushort*)p; p += SZ_ACT;

  const int nAct = MDIM * KDIM;          // 16,777,216
  const int nW   = NDIM * KDIM;          //  4,194,304
  const float NS = (float)sqrt(2.0 * log(1.25 / 1e-5));
  const float SCALE = (float)(1.0 / sqrt((double)HD));

  cvt_bf16<<<dim3(nAct / 1024), dim3(256), 0, stream>>>(query, qb);
  cvt_bf16<<<dim3(nAct / 1024), dim3(256), 0, stream>>>(key_t, kb);
  cvt_bf16<<<dim3(nAct / 1024), dim3(256), 0, stream>>>(value, vb);
  cvt_bf16<<<dim3(nW / 1024),   dim3(256), 0, stream>>>(Wq, wqb);
  cvt_bf16<<<dim3(nW / 1024),   dim3(256), 0, stream>>>(Wk, wkb);
  cvt_bf16<<<dim3(nW / 1024),   dim3(256), 0, stream>>>(Wv, wvb);
  cvt_bf16<<<dim3(nW / 1024),   dim3(256), 0, stream>>>(Wo, wob);

  dim3 ggrid(MDIM / 128, NDIM / 128);   // 64 x 16
  gemm_nt<1><<<ggrid, dim3(256), 0, stream>>>(qb, wqb, bq, (void*)Qh);
  gemm_nt<1><<<ggrid, dim3(256), 0, stream>>>(kb, wkb, bk, (void*)Kh);
  gemm_nt<2><<<ggrid, dim3(256), 0, stream>>>(vb, wvb, bv, (void*)Vt);

  attn_kernel<<<dim3(SEQ / 128, BATCH * NH), dim3(256), 0, stream>>>(
      Qh, Kh, Vt, noise, ctxn, SCALE, NS);

  gemm_nt<0><<<ggrid, dim3(256), 0, stream>>>(ctxn, wob, bo, d_out);
}